// Round 8
// baseline (116.762 us; speedup 1.0000x reference)
//
#include <hip/hip_runtime.h>
#include <stdint.h>
#include <stddef.h>

// BalancedFocalLoss fused kernel — MI355X (gfx950), round 6 kernel (3rd submit;
// R6/R7 benches failed on GPU acquisition, kernel still unmeasured)
//
//   z = concat(zx, zy); zn = z/||z||;  sim = zn·znT / 0.5
//   ce_i  = log( sum_{j != i} exp(sim_ij) ) - sim_{i,(i+B)%N}
//   out   = mean( ALPHA * (1-exp(-ce))^2 * ce )
//
// s2n = sqrt(2*log2e)*zn bf16 => acc = log2e*sim; exp(sim) == exp2(acc).
// Upper-triangle 128^2 tiles only (2080); each tile emits row-sums (slot
// q*2+wc) and col-sums (slot p*2+wr) — 128 slots/row, each written once.
//
// R6: occupancy lever. BK=32 double-buffer -> LDS 32 KiB/block (was 64),
// grid 1040 blocks x 2 tiles (2080 exact, no straggler tail) -> ~4 resident
// blocks/CU (was 2). The 2-phase loop's vmcnt(0)+barrier drain is now hidden
// by 3 other resident blocks' MFMA/VALU (m114 mechanism). zn (4 MiB) fits a
// single XCD L2, so stage latency is L2-class; swizzle re-derived for BK=32
// (units of 16B: 4/row; XOR r&3) — lands on the 8-phase b128 bank minimum.

typedef __attribute__((ext_vector_type(8))) short short8;
typedef __attribute__((ext_vector_type(4))) float f32x4;

#define NROWS 8192
#define DDIM 256
#define NTILES 2080   // 64*65/2 panels of 128
#define NBLK 1040     // 2 tiles per block

__device__ __forceinline__ unsigned short f2bf(float f) {
  unsigned int u = __float_as_uint(f);
  u = (u + 0x7FFFu + ((u >> 16) & 1u)) >> 16;   // RNE, inputs finite
  return (unsigned short)u;
}

__device__ __forceinline__ void unrank_tile(int t, int& p_out, int& q_out) {
  // triangular pair (p <= q), rank(p,q) = p*(129-p)/2 + (q-p)
  int p = (int)((129.0f - sqrtf((float)(16641 - 8 * t))) * 0.5f);
  p = max(0, min(63, p));
  while ((((p + 1) * (129 - (p + 1))) >> 1) <= t) ++p;
  while (((p * (129 - p)) >> 1) > t) --p;
  p_out = p;
  q_out = p + (t - ((p * (129 - p)) >> 1));
}

// ---------------- 1. normalize + sqrt(2*log2e) scale + bf16; zero d1 counter ----------------
__global__ __launch_bounds__(256) void norm_kernel(const float* __restrict__ zx,
                                                   const float* __restrict__ zy,
                                                   unsigned short* __restrict__ zn,
                                                   unsigned int* __restrict__ counter) {
  if (blockIdx.x == 0 && threadIdx.x == 0) *counter = 0u;
  const int row = blockIdx.x * 4 + (threadIdx.x >> 6);   // 8192 rows, 1 per wave
  const int lane = threadIdx.x & 63;
  const float* src = (row < 4096) ? (zx + (size_t)row * DDIM)
                                  : (zy + (size_t)(row - 4096) * DDIM);
  float4 v = reinterpret_cast<const float4*>(src)[lane];
  float ss = v.x * v.x + v.y * v.y + v.z * v.z + v.w * v.w;
#pragma unroll
  for (int m = 1; m < 64; m <<= 1) ss += __shfl_xor(ss, m);
  const float sc = 1.69864360f * rsqrtf(ss);   // sqrt(2*log2e)/||z||
  ushort4 o;
  o.x = f2bf(v.x * sc); o.y = f2bf(v.y * sc);
  o.z = f2bf(v.z * sc); o.w = f2bf(v.w * sc);
  reinterpret_cast<ushort4*>(zn + (size_t)row * DDIM)[lane] = o;
}

// ---------------- 2. upper-triangle sim GEMM + exp2 row/col sums ----------------
__global__ __launch_bounds__(256, 4) void simtri_kernel(const unsigned short* __restrict__ zn,
                                                        float* __restrict__ partial,
                                                        float* __restrict__ pos) {
  __shared__ unsigned short smem[2][2][128 * 32];   // 32 KiB total
  // XCD-contiguous chunk id: same-XCD blocks (bid%8) get consecutive chunks
  // -> consecutive row-major tile pairs share A/B panels in that XCD's L2.
  const int c = (blockIdx.x & 7) * 130 + (blockIdx.x >> 3);   // bijective, 1040=8*130

  const int tid = threadIdx.x;
  const int lane = tid & 63;
  const int wid = tid >> 6;
  const int wr = wid >> 1;              // wave row (0/1)
  const int wc = wid & 1;               // wave col (0/1)
  const int hi = lane >> 4, lo = lane & 15;
  const int sw = lo & 3;                // frag-read XOR (== row&3 of this lane's rows)

  const f32x4 z4 = {0.f, 0.f, 0.f, 0.f};
  f32x4 acc[4][4];
#pragma unroll
  for (int m = 0; m < 4; ++m)
#pragma unroll
    for (int n = 0; n < 4; ++n) acc[m][n] = z4;

  // Stage 128x32 bf16 tile (8 KiB = 512 x 16B units, 256 thr x 2).
  // LDS dest LINEAR (global_load_lds requirement); global source pre-swizzled
  // so LDS[r][ul] holds global unit (ul ^ (r&3)); read applies the same XOR.
  auto stage_one = [&](int buf, int which, int row0, int k0) {
    unsigned short* lb = &smem[buf][which][0];
#pragma unroll
    for (int j = 0; j < 2; ++j) {
      const int u = j * 256 + tid;                 // 16B-unit index, 0..511
      const int r = u >> 2, ul = u & 3;            // 4 units per 32-k row
      const unsigned short* g =
          zn + (size_t)(row0 + r) * DDIM + k0 + ((ul ^ (r & 3)) << 3);
      unsigned short* l = lb + (size_t)(j * 256 + wid * 64) * 8;  // wave-uniform; HW adds lane*16B
      __builtin_amdgcn_global_load_lds(
          (const __attribute__((address_space(1))) void*)g,
          (__attribute__((address_space(3))) void*)l, 16, 0, 0);
    }
  };
  auto stageT = [&](int buf, int p, int q, int k0) {
    stage_one(buf, 0, p << 7, k0);
    if (p != q) stage_one(buf, 1, q << 7, k0);
  };

  int cp, cq;
  unrank_tile(2 * c, cp, cq);
  stageT(0, cp, cq, 0);
  __syncthreads();

  int buf = 0;
  for (int i = 0; i < 2; ++i) {
    // next tile: row-major successor within the triangle (rank 2c -> 2c+1)
    int np = cp, nq = cq;
    const bool have_next = (i == 0);
    if (have_next) { if (cq == 63) { np = cp + 1; nq = np; } else { nq = cq + 1; } }
    const bool isdiag = (cp == cq);
    const bool ispos = (cq == cp + 32);
    const int R0 = cp << 7;
    const int C0 = cq << 7;

#pragma unroll
    for (int kk = 0; kk < 8; ++kk) {               // K=256 in steps of 32
      if (kk < 7) stageT(buf ^ 1, cp, cq, (kk + 1) * 32);
      else if (have_next) stageT(buf ^ 1, np, nq, 0);
      const unsigned short* A = &smem[buf][0][0];
      const unsigned short* Bm = isdiag ? A : &smem[buf][1][0];
      short8 af[4], bfr[4];
#pragma unroll
      for (int m = 0; m < 4; ++m)
        af[m] = *reinterpret_cast<const short8*>(
            A + ((wr * 64 + m * 16 + lo) * 32 + ((hi ^ sw) << 3)));
#pragma unroll
      for (int n = 0; n < 4; ++n)
        bfr[n] = *reinterpret_cast<const short8*>(
            Bm + ((wc * 64 + n * 16 + lo) * 32 + ((hi ^ sw) << 3)));
#pragma unroll
      for (int m = 0; m < 4; ++m)
#pragma unroll
        for (int n = 0; n < 4; ++n)
          acc[m][n] = __builtin_amdgcn_mfma_f32_16x16x32_bf16(af[m], bfr[n], acc[m][n], 0, 0, 0);
      buf ^= 1;
      if (kk < 7) __syncthreads();
    }

    // ---- epilogue (before tile-boundary barrier: overlaps staged-load latency) ----
    float rsum[4][4];       // [m][r]  row partial over this wave's 64 cols
    float csum[4];          // [n]     col partial over this wave's 64 rows
#pragma unroll
    for (int m = 0; m < 4; ++m)
#pragma unroll
      for (int r = 0; r < 4; ++r) rsum[m][r] = 0.f;
#pragma unroll
    for (int n = 0; n < 4; ++n) csum[n] = 0.f;

#pragma unroll
    for (int m = 0; m < 4; ++m)
#pragma unroll
      for (int n = 0; n < 4; ++n)
#pragma unroll
        for (int r = 0; r < 4; ++r) {
          const float e = __builtin_amdgcn_exp2f(acc[m][n][r]);
          rsum[m][r] += e;
          csum[n] += e;
        }

    // fixups: diag-exclude / pos harvest (tile-local diagonal, wr==wc waves only)
    if ((isdiag || ispos) && (wr == wc)) {
#pragma unroll
      for (int m = 0; m < 4; ++m)
#pragma unroll
        for (int r = 0; r < 4; ++r)
          if (lo == 4 * hi + r) {
            if (isdiag) rsum[m][r] -= __builtin_amdgcn_exp2f(acc[m][m][r]);
            else        pos[R0 + wr * 64 + m * 16 + lo] = acc[m][m][r];  // log2-domain
          }
    }

    // row-sums: reduce across 16 col-lanes -> slot q*2+wc
#pragma unroll
    for (int m = 0; m < 4; ++m)
#pragma unroll
      for (int r = 0; r < 4; ++r) {
        float s = rsum[m][r];
        s += __shfl_xor(s, 1); s += __shfl_xor(s, 2);
        s += __shfl_xor(s, 4); s += __shfl_xor(s, 8);
        if (lo == 0) {
          const int grow = R0 + wr * 64 + m * 16 + (hi << 2) + r;
          partial[(size_t)(cq * 2 + wc) * NROWS + grow] = s;
        }
      }

    // col-sums: reduce across 4 row-groups -> slot p*2+wr (skip diagonal tile)
    if (!isdiag) {
#pragma unroll
      for (int n = 0; n < 4; ++n) {
        float cs = csum[n];
        cs += __shfl_xor(cs, 16); cs += __shfl_xor(cs, 32);
        if (lane < 16)
          partial[(size_t)(cp * 2 + wr) * NROWS + (C0 + wc * 64 + n * 16 + lane)] = cs;
      }
    }

    // reset acc for next tile
#pragma unroll
    for (int m = 0; m < 4; ++m)
#pragma unroll
      for (int n = 0; n < 4; ++n) acc[m][n] = z4;

    __syncthreads();   // next-tile staged data ready; smem[buf^1] safe to overwrite
    cp = np; cq = nq;
  }
}

// ---------------- 3. per-row loss + full reduction (last-block-done finish) ----------------
__global__ __launch_bounds__(256) void d1_kernel(const float* __restrict__ partial,
                                                 const float* __restrict__ pos,
                                                 float* __restrict__ bsum,
                                                 float* __restrict__ out,
                                                 unsigned int* __restrict__ counter) {
  const int row = blockIdx.x * 256 + threadIdx.x;   // 32 blocks x 256
  float s = 0.f;
#pragma unroll 16
  for (int c = 0; c < 128; ++c) s += partial[(size_t)c * NROWS + row];
  const float L = __log2f(s) - pos[row & 4095];     // log2-domain ce
  const float pt = __builtin_amdgcn_exp2f(-L);
  const float ce = 0.69314718056f * L;
  float f = (1.f - pt) * (1.f - pt) * ce;
#pragma unroll
  for (int m = 1; m < 64; m <<= 1) f += __shfl_xor(f, m);
  __shared__ float wsum[4];
  if ((threadIdx.x & 63) == 0) wsum[threadIdx.x >> 6] = f;
  __syncthreads();
  if (threadIdx.x == 0) {
    bsum[blockIdx.x] = wsum[0] + wsum[1] + wsum[2] + wsum[3];
    __threadfence();
    if (atomicAdd(counter, 1u) == 31u) {        // last block: deterministic finish
      __threadfence();
      float v = 0.f;
#pragma unroll
      for (int c = 0; c < 32; ++c) v += ((const volatile float*)bsum)[c];
      out[0] = 0.25f * v / 8192.f;              // ALPHA * mean
    }
  }
}

extern "C" void kernel_launch(void* const* d_in, const int* in_sizes, int n_in,
                              void* d_out, int out_size, void* d_ws, size_t ws_size,
                              hipStream_t stream) {
  const float* zx = (const float*)d_in[0];
  const float* zy = (const float*)d_in[1];
  float* out = (float*)d_out;

  // workspace (~8.02 MiB): zn bf16 | pos | partial | bsum | counter
  unsigned short* zn = (unsigned short*)d_ws;                      // 8192*256*2 = 4 MiB
  float* pos = (float*)((char*)d_ws + (size_t)NROWS * DDIM * 2);   // 16 KiB
  float* partial = pos + 4096;                                     // 128*8192*4 = 4 MiB
  float* bsum = partial + (size_t)128 * NROWS;                     // 128 B
  unsigned int* counter = (unsigned int*)(bsum + 32);              // 4 B

  norm_kernel<<<2048, 256, 0, stream>>>(zx, zy, zn, counter);
  simtri_kernel<<<NBLK, 256, 0, stream>>>(zn, partial, pos);
  d1_kernel<<<32, 256, 0, stream>>>(partial, pos, bsum, out, counter);
}

// Round 9
// 111.502 us; speedup vs baseline: 1.0472x; 1.0472x over previous
//
#include <hip/hip_runtime.h>
#include <stdint.h>
#include <stddef.h>

// BalancedFocalLoss fused kernel — MI355X (gfx950), round 9
//
//   z = concat(zx, zy); zn = z/||z||;  sim = zn·znT / 0.5
//   ce_i  = log( sum_{j != i} exp(sim_ij) ) - sim_{i,(i+B)%N}
//   out   = mean( ALPHA * (1-exp(-ce))^2 * ce )
//
// s2n = sqrt(2*log2e)*zn bf16 => acc = log2e*sim; exp(sim) == exp2(acc).
// Upper-triangle 128^2 tiles only (2080); each tile emits row-sums (slot
// q*2+wc) and col-sums (slot p*2+wr) — 128 slots/row, each written once.
//
// R9: T4 counted-vmcnt pipeline (m201 template pattern). Triple-buffered
// BK=32 stages (48 KiB LDS), prologue stages 3 steps ahead; each step:
//   s_waitcnt vmcnt(8) ; s_barrier ; ds_read+MFMA ; [epilogue] ; s_barrier ;
//   stage step k+3 (4 global_load_lds per wave, constant count)
// The per-step vmcnt(0) drain of __syncthreads (R5/R8's dominant stall —
// just-issued stage latency serialized on the critical path) is gone: loads
// complete ~3 steps (≈1000 cy) before their wait. Tail peeled vmcnt(4)/(0).
// Diag tiles stage B redundantly to keep 4 loads/wave/step exact.

typedef __attribute__((ext_vector_type(8))) short short8;
typedef __attribute__((ext_vector_type(4))) float f32x4;

#define NROWS 8192
#define DDIM 256
#define NTILES 2080   // 64*65/2 panels of 128
#define NBLK 512

__device__ __forceinline__ unsigned short f2bf(float f) {
  unsigned int u = __float_as_uint(f);
  u = (u + 0x7FFFu + ((u >> 16) & 1u)) >> 16;   // RNE, inputs finite
  return (unsigned short)u;
}

__device__ __forceinline__ void unrank_tile(int t, int& p_out, int& q_out) {
  // triangular pair (p <= q), rank(p,q) = p*(129-p)/2 + (q-p)
  int p = (int)((129.0f - sqrtf((float)(16641 - 8 * t))) * 0.5f);
  p = max(0, min(63, p));
  while ((((p + 1) * (129 - (p + 1))) >> 1) <= t) ++p;
  while (((p * (129 - p)) >> 1) > t) --p;
  p_out = p;
  q_out = p + (t - ((p * (129 - p)) >> 1));
}

// ---------------- 1. normalize + sqrt(2*log2e) scale + bf16; zero d1 counter ----------------
__global__ __launch_bounds__(256) void norm_kernel(const float* __restrict__ zx,
                                                   const float* __restrict__ zy,
                                                   unsigned short* __restrict__ zn,
                                                   unsigned int* __restrict__ counter) {
  if (blockIdx.x == 0 && threadIdx.x == 0) *counter = 0u;
  const int row = blockIdx.x * 4 + (threadIdx.x >> 6);   // 8192 rows, 1 per wave
  const int lane = threadIdx.x & 63;
  const float* src = (row < 4096) ? (zx + (size_t)row * DDIM)
                                  : (zy + (size_t)(row - 4096) * DDIM);
  float4 v = reinterpret_cast<const float4*>(src)[lane];
  float ss = v.x * v.x + v.y * v.y + v.z * v.z + v.w * v.w;
#pragma unroll
  for (int m = 1; m < 64; m <<= 1) ss += __shfl_xor(ss, m);
  const float sc = 1.69864360f * rsqrtf(ss);   // sqrt(2*log2e)/||z||
  ushort4 o;
  o.x = f2bf(v.x * sc); o.y = f2bf(v.y * sc);
  o.z = f2bf(v.z * sc); o.w = f2bf(v.w * sc);
  reinterpret_cast<ushort4*>(zn + (size_t)row * DDIM)[lane] = o;
}

// ---------------- 2. upper-triangle sim GEMM + exp2 row/col sums ----------------
__global__ __launch_bounds__(256, 2) void simtri_kernel(const unsigned short* __restrict__ zn,
                                                        float* __restrict__ partial,
                                                        float* __restrict__ pos) {
  __shared__ unsigned short smem[3][2][128 * 32];   // 48 KiB triple-buffer
  // XCD-contiguous chunk id: same-XCD blocks (bid%8) own consecutive
  // row-major tile runs -> shared A/B panels stay hot in that XCD's L2.
  const int c = (blockIdx.x & 7) * 64 + (blockIdx.x >> 3);   // bijective, 512=8*64
  int start, nt;
  if (c < 32) { start = c * 5;              nt = 5; }   // 2080 = 32*5 + 480*4
  else        { start = 160 + (c - 32) * 4; nt = 4; }
  const int NS = nt * 8;                                // K32-steps, 32 or 40

  const int tid = threadIdx.x;
  const int lane = tid & 63;
  const int wid = tid >> 6;
  const int wr = wid >> 1;              // wave row (0/1)
  const int wc = wid & 1;               // wave col (0/1)
  const int hi = lane >> 4, lo = lane & 15;
  const int sw = lo & 3;                // frag-read XOR (== row&3 of this lane's rows)

  const f32x4 z4 = {0.f, 0.f, 0.f, 0.f};
  f32x4 acc[4][4];
#pragma unroll
  for (int m = 0; m < 4; ++m)
#pragma unroll
    for (int n = 0; n < 4; ++n) acc[m][n] = z4;

  // Stage one K32-step of tiles (p,q) into buffer b: A rows p*128, B rows
  // q*128 — ALWAYS both halves (constant 4 global_load_lds per wave so the
  // counted vmcnt stays exact; diag tiles stage B redundantly).
  // LDS dest LINEAR; global source pre-swizzled (unit ul ^ (r&3)); frag
  // reads apply the same XOR — bank-conflict-free (b128 8-phase minimum).
  auto stage_pair = [&](int b, int p, int q, int k0) {
#pragma unroll
    for (int which = 0; which < 2; ++which) {
      const int row0 = (which ? q : p) << 7;
      unsigned short* lb = &smem[b][which][0];
#pragma unroll
      for (int j = 0; j < 2; ++j) {
        const int u = j * 256 + tid;               // 16B-unit index, 0..511
        const int r = u >> 2, ul = u & 3;          // 4 units per 32-k row
        const unsigned short* g =
            zn + (size_t)(row0 + r) * DDIM + k0 + ((ul ^ (r & 3)) << 3);
        unsigned short* l = lb + (size_t)(j * 256 + wid * 64) * 8;  // wave-uniform
        __builtin_amdgcn_global_load_lds(
            (const __attribute__((address_space(1))) void*)g,
            (__attribute__((address_space(3))) void*)l, 16, 0, 0);
      }
    }
  };

  auto consume = [&](int b) {
    const unsigned short* A = &smem[b][0][0];
    const unsigned short* Bm = &smem[b][1][0];
    short8 af[4], bfr[4];
#pragma unroll
    for (int m = 0; m < 4; ++m)
      af[m] = *reinterpret_cast<const short8*>(
          A + ((wr * 64 + m * 16 + lo) * 32 + ((hi ^ sw) << 3)));
#pragma unroll
    for (int n = 0; n < 4; ++n)
      bfr[n] = *reinterpret_cast<const short8*>(
          Bm + ((wc * 64 + n * 16 + lo) * 32 + ((hi ^ sw) << 3)));
#pragma unroll
    for (int m = 0; m < 4; ++m)
#pragma unroll
      for (int n = 0; n < 4; ++n)
        acc[m][n] = __builtin_amdgcn_mfma_f32_16x16x32_bf16(af[m], bfr[n], acc[m][n], 0, 0, 0);
  };

  auto advance = [&](int& p, int& q) {
    if (q == 63) { ++p; q = p; } else { ++q; }
  };

  auto epilogue = [&](int cp, int cq) {
    const bool isdiag = (cp == cq);
    const bool ispos = (cq == cp + 32);
    const int R0 = cp << 7;
    const int C0 = cq << 7;
    float rsum[4][4];       // [m][r] row partial over this wave's 64 cols
    float csum[4];          // [n]    col partial over this wave's 64 rows
#pragma unroll
    for (int m = 0; m < 4; ++m)
#pragma unroll
      for (int r = 0; r < 4; ++r) rsum[m][r] = 0.f;
#pragma unroll
    for (int n = 0; n < 4; ++n) csum[n] = 0.f;
#pragma unroll
    for (int m = 0; m < 4; ++m)
#pragma unroll
      for (int n = 0; n < 4; ++n)
#pragma unroll
        for (int r = 0; r < 4; ++r) {
          const float e = __builtin_amdgcn_exp2f(acc[m][n][r]);
          rsum[m][r] += e;
          csum[n] += e;
        }
    // fixups: diag-exclude / pos harvest (tile-local diagonal, wr==wc waves)
    if ((isdiag || ispos) && (wr == wc)) {
#pragma unroll
      for (int m = 0; m < 4; ++m)
#pragma unroll
        for (int r = 0; r < 4; ++r)
          if (lo == 4 * hi + r) {
            if (isdiag) rsum[m][r] -= __builtin_amdgcn_exp2f(acc[m][m][r]);
            else        pos[R0 + wr * 64 + m * 16 + lo] = acc[m][m][r];  // log2-domain
          }
    }
    // row-sums: reduce across 16 col-lanes -> slot q*2+wc
#pragma unroll
    for (int m = 0; m < 4; ++m)
#pragma unroll
      for (int r = 0; r < 4; ++r) {
        float s = rsum[m][r];
        s += __shfl_xor(s, 1); s += __shfl_xor(s, 2);
        s += __shfl_xor(s, 4); s += __shfl_xor(s, 8);
        if (lo == 0) {
          const int grow = R0 + wr * 64 + m * 16 + (hi << 2) + r;
          partial[(size_t)(cq * 2 + wc) * NROWS + grow] = s;
        }
      }
    // col-sums: reduce across 4 row-groups -> slot p*2+wr (skip diagonal tile)
    if (!isdiag) {
#pragma unroll
      for (int n = 0; n < 4; ++n) {
        float cs = csum[n];
        cs += __shfl_xor(cs, 16); cs += __shfl_xor(cs, 32);
        if (lane < 16)
          partial[(size_t)(cp * 2 + wr) * NROWS + (C0 + wc * 64 + n * 16 + lane)] = cs;
      }
    }
  };

  // ---- pipeline ----
  int cp, cq;                 // consume-tile pointer
  unrank_tile(start, cp, cq);
  int sp = cp, sq = cq;       // stage-tile pointer (steps 0..2 are kk=0..2 of tile 0)
  stage_pair(0, sp, sq, 0);
  stage_pair(1, sp, sq, 32);
  stage_pair(2, sp, sq, 64);

  int bsel = 0;
  for (int k = 0; k < NS - 2; ++k) {
    asm volatile("s_waitcnt vmcnt(8)" ::: "memory");   // step-k loads done; k+1,k+2 in flight
    __builtin_amdgcn_s_barrier();                      // buf[bsel] fully written, all waves
    __builtin_amdgcn_sched_barrier(0);
    consume(bsel);
    if ((k & 7) == 7) {                                // tile finished
      epilogue(cp, cq);
      advance(cp, cq);
#pragma unroll
      for (int m = 0; m < 4; ++m)
#pragma unroll
        for (int n = 0; n < 4; ++n) acc[m][n] = z4;
    }
    __builtin_amdgcn_s_barrier();                      // all waves done reading buf[bsel]
    const int t = k + 3;
    if (t < NS) {
      if ((t & 7) == 0) advance(sp, sq);
      stage_pair(bsel, sp, sq, (t & 7) * 32);          // 4 loads/wave, overwrite freed buf
    }
    bsel = (bsel == 2) ? 0 : bsel + 1;
  }
  // peeled tail: k = NS-2 (kk=6), only 8 loads in flight
  asm volatile("s_waitcnt vmcnt(4)" ::: "memory");
  __builtin_amdgcn_s_barrier();
  __builtin_amdgcn_sched_barrier(0);
  consume(bsel);
  bsel = (bsel == 2) ? 0 : bsel + 1;
  // k = NS-1 (kk=7), last 4 loads
  asm volatile("s_waitcnt vmcnt(0)" ::: "memory");
  __builtin_amdgcn_s_barrier();
  __builtin_amdgcn_sched_barrier(0);
  consume(bsel);
  epilogue(cp, cq);
}

// ---------------- 3. per-row loss + full reduction (last-block-done finish) ----------------
__global__ __launch_bounds__(256) void d1_kernel(const float* __restrict__ partial,
                                                 const float* __restrict__ pos,
                                                 float* __restrict__ bsum,
                                                 float* __restrict__ out,
                                                 unsigned int* __restrict__ counter) {
  const int row = blockIdx.x * 256 + threadIdx.x;   // 32 blocks x 256
  float s = 0.f;
#pragma unroll 16
  for (int c = 0; c < 128; ++c) s += partial[(size_t)c * NROWS + row];
  const float L = __log2f(s) - pos[row & 4095];     // log2-domain ce
  const float pt = __builtin_amdgcn_exp2f(-L);
  const float ce = 0.69314718056f * L;
  float f = (1.f - pt) * (1.f - pt) * ce;
#pragma unroll
  for (int m = 1; m < 64; m <<= 1) f += __shfl_xor(f, m);
  __shared__ float wsum[4];
  if ((threadIdx.x & 63) == 0) wsum[threadIdx.x >> 6] = f;
  __syncthreads();
  if (threadIdx.x == 0) {
    bsum[blockIdx.x] = wsum[0] + wsum[1] + wsum[2] + wsum[3];
    __threadfence();
    if (atomicAdd(counter, 1u) == 31u) {        // last block: deterministic finish
      __threadfence();
      float v = 0.f;
#pragma unroll
      for (int c = 0; c < 32; ++c) v += ((const volatile float*)bsum)[c];
      out[0] = 0.25f * v / 8192.f;              // ALPHA * mean
    }
  }
}

extern "C" void kernel_launch(void* const* d_in, const int* in_sizes, int n_in,
                              void* d_out, int out_size, void* d_ws, size_t ws_size,
                              hipStream_t stream) {
  const float* zx = (const float*)d_in[0];
  const float* zy = (const float*)d_in[1];
  float* out = (float*)d_out;

  // workspace (~8.02 MiB): zn bf16 | pos | partial | bsum | counter
  unsigned short* zn = (unsigned short*)d_ws;                      // 8192*256*2 = 4 MiB
  float* pos = (float*)((char*)d_ws + (size_t)NROWS * DDIM * 2);   // 16 KiB
  float* partial = pos + 4096;                                     // 128*8192*4 = 4 MiB
  float* bsum = partial + (size_t)128 * NROWS;                     // 128 B
  unsigned int* counter = (unsigned int*)(bsum + 32);              // 4 B

  norm_kernel<<<2048, 256, 0, stream>>>(zx, zy, zn, counter);
  simtri_kernel<<<NBLK, 256, 0, stream>>>(zn, partial, pos);
  d1_kernel<<<32, 256, 0, stream>>>(partial, pos, bsum, out, counter);
}